// Round 5
// baseline (222.511 us; speedup 1.0000x reference)
//
#include <hip/hip_runtime.h>
#include <hip/hip_cooperative_groups.h>
#include <math.h>

namespace cg = cooperative_groups;

#define C_DIM 256
#define H_DIM 128
#define W_DIM 128
#define HW (H_DIM*W_DIM)
#define N_ROIS 512
#define TOKENS (N_ROIS*49)
#define SPS 0.0625f             // spatial scale
#define GAMMA 0.1f
#define SCALE 0.0625f           // d^-0.5 = 1/16

typedef __attribute__((ext_vector_type(8))) short bf16x8;
typedef __attribute__((ext_vector_type(4))) float f32x4;
typedef __attribute__((ext_vector_type(8))) unsigned short us8;

__device__ inline unsigned short f2bf_rne(float f) {
    unsigned int b = __float_as_uint(f);
    b += 0x7fffu + ((b >> 16) & 1u);
    return (unsigned short)(b >> 16);
}
__device__ inline float bfu(unsigned short u) {
    return __uint_as_float(((unsigned int)u) << 16);
}

// =================== shared phase bodies (used by mega AND fallback) ===================

// pre1: A_k = Wk@W_proj, A_v = Wv@W_proj, Qhat = queries@Wq.T + bq, cv = Wv@b_proj + bv
__device__ inline void dev_pre1(int idx,
                                const float* w_proj, const float* in_proj_w,
                                const float* in_proj_b, const float* queries,
                                const float* b_proj,
                                float* A_k, float* A_v, float* Qhat, float* cv) {
    if (idx < 65536) {
        int i = idx >> 8, j = idx & 255;
        const float* wk = in_proj_w + (size_t)(256 + i) * 256;
        float s = 0.f;
        for (int t = 0; t < 256; t++) s += wk[t] * w_proj[t * 256 + j];
        A_k[idx] = s;
    } else if (idx < 131072) {
        int e = idx - 65536;
        int i = e >> 8, j = e & 255;
        const float* wv = in_proj_w + (size_t)(512 + i) * 256;
        float s = 0.f;
        for (int t = 0; t < 256; t++) s += wv[t] * w_proj[t * 256 + j];
        A_v[e] = s;
    } else if (idx < 143616) {
        int e = idx - 131072;
        int s_ = e >> 8, i = e & 255;
        const float* q  = queries + (size_t)s_ * 256;
        const float* wq = in_proj_w + (size_t)i * 256;
        float s = in_proj_b[i];
        for (int t = 0; t < 256; t++) s += q[t] * wq[t];
        Qhat[e] = s;
    } else if (idx < 143872) {
        int i = idx - 143616;
        const float* wv = in_proj_w + (size_t)(512 + i) * 256;
        float s = in_proj_b[512 + i];
        for (int t = 0; t < 256; t++) s += wv[t] * b_proj[t];
        cv[i] = s;
    }
}

// pre2: u = Qhat@A_k, M = W_o@A_v (bf16 hi/lo split), c_out = W_o@cv + b_o
__device__ inline void dev_pre2(int idx,
                                const float* Qhat, const float* A_k, const float* A_v,
                                const float* out_proj_w, const float* out_proj_b,
                                const float* cv,
                                float* u, unsigned short* Mh, unsigned short* Ml,
                                float* c_out) {
    if (idx < 12544) {
        int s_ = idx >> 8, j = idx & 255;
        const float* qh = Qhat + (size_t)s_ * 256;
        float s = 0.f;
        for (int i = 0; i < 256; i++) s += qh[i] * A_k[i * 256 + j];
        u[idx] = s;
    } else if (idx < 78080) {
        int e = idx - 12544;
        int c = e >> 8, d = e & 255;
        const float* wo = out_proj_w + (size_t)c * 256;
        float s = 0.f;
        for (int i = 0; i < 256; i++) s += wo[i] * A_v[i * 256 + d];
        unsigned short hi = f2bf_rne(s);
        unsigned short lo = f2bf_rne(s - bfu(hi));
        Mh[(size_t)c * 256 + d] = hi;
        Ml[(size_t)c * 256 + d] = lo;
    } else if (idx < 78336) {
        int c = idx - 78080;
        const float* wo = out_proj_w + (size_t)c * 256;
        float s = out_proj_b[c];
        for (int i = 0; i < 256; i++) s += wo[i] * cv[i];
        c_out[c] = s;
    }
}

// one 64ch x 64sp transpose tile: NCHW fp32 -> NHWC bf16 (uses 16640 B of lds)
__device__ inline void dev_transpose_tile(char* ldsraw, int tile_id, int tid,
                                          const float* features,
                                          unsigned short* feat_b) {
    float (*tile)[65] = (float (*)[65])ldsraw;
    int b   = tile_id >> 10;            // 4096 tiles: b(4) x c-grp(4) x s-grp(256)
    int rem = tile_id & 1023;
    int c0  = (rem >> 8) << 6;
    int s0  = (rem & 255) << 6;
    int sl = tid & 63, cw = tid >> 6;
    const float* fin = features + (size_t)b * C_DIM * HW;
    #pragma unroll
    for (int kk = 0; kk < 16; kk++) {
        int cl = cw + kk * 4;
        tile[cl][sl] = fin[(size_t)(c0 + cl) * HW + s0 + sl];
    }
    __syncthreads();
    unsigned short* fo = feat_b + (size_t)b * HW * C_DIM;
    #pragma unroll
    for (int kk = 0; kk < 16; kk++) {
        int sl2 = cw + kk * 4;
        fo[(size_t)(s0 + sl2) * C_DIM + c0 + sl] = f2bf_rne(tile[sl][sl2]);
    }
    __syncthreads();
}

// fused per-roi: sample + softmax-mix -> LDS bf16 A-tile -> MFMA GEMM -> out
// (uses 54272 B of lds; m reads complete before epilogue overwrite)
__device__ inline void dev_sample_gemm(char* ldsraw, int n, int tid,
                                       const unsigned short* feat_b,
                                       const float* rois, const float* offs,
                                       const float* u,
                                       const unsigned short* Mh,
                                       const unsigned short* Ml,
                                       const float* c_out, float* out) {
    unsigned short* A = (unsigned short*)ldsraw;   // [64][264] bf16

    const float* r = rois + (size_t)n * 5;
    int bi    = (int)r[0];
    float x1  = r[1] * SPS - 0.5f;
    float y1v = r[2] * SPS - 0.5f;
    float rw  = r[3] * SPS - 0.5f - x1;
    float rh  = r[4] * SPS - 0.5f - y1v;
    float bw  = rw * (1.0f / 7.0f);
    float bh  = rh * (1.0f / 7.0f);
    const unsigned short* fb = feat_b + (size_t)bi * HW * C_DIM;

    int lane32 = tid & 31;
    int halfw  = tid >> 5;
    int c8 = lane32 * 8;

    for (int t = halfw; t < 49; t += 8) {
        int hb = t / 7, wb = t - hb * 7;
        const float* up = u + (size_t)t * 256 + c8;
        float uu[8];
        *(float4*)uu       = *(const float4*)up;
        *(float4*)(uu + 4) = *(const float4*)(up + 4);

        float sv[4][8];
        float part[4];
        #pragma unroll
        for (int p = 0; p < 4; p++) {              // sequential p: low reg pressure
            float offw = offs[((p * 7 + hb) * 7 + wb) * 2 + 0];
            float offh = offs[((p * 7 + hb) * 7 + wb) * 2 + 1];
            float y = y1v + ((float)hb + 0.5f) * bh + GAMMA * rh * offh;
            float x = x1  + ((float)wb + 0.5f) * bw + GAMMA * rw * offw;
            bool valid = (y > -1.0f) && (y < 128.0f) && (x > -1.0f) && (x < 128.0f);
            float yc = fminf(fmaxf(y, 0.f), 127.f);
            float xc = fminf(fmaxf(x, 0.f), 127.f);
            int y0i = (int)yc, x0i = (int)xc;      // >=0: trunc == floor
            int y1i = min(y0i + 1, 127), x1i = min(x0i + 1, 127);
            float ly = yc - (float)y0i, lx = xc - (float)x0i;
            float hy = 1.f - ly, hx = 1.f - lx;
            float w00 = hy * hx, w01 = hy * lx, w10 = ly * hx, w11 = ly * lx;
            if (!valid) { w00 = 0.f; w01 = 0.f; w10 = 0.f; w11 = 0.f; }
            us8 r00 = *(const us8*)(fb + (size_t)(y0i * W_DIM + x0i) * 256 + c8);
            us8 r01 = *(const us8*)(fb + (size_t)(y0i * W_DIM + x1i) * 256 + c8);
            us8 r10 = *(const us8*)(fb + (size_t)(y1i * W_DIM + x0i) * 256 + c8);
            us8 r11 = *(const us8*)(fb + (size_t)(y1i * W_DIM + x1i) * 256 + c8);
            float accp = 0.f;
            #pragma unroll
            for (int j = 0; j < 8; j++) {
                float v = w00 * bfu(r00[j]) + w01 * bfu(r01[j])
                        + w10 * bfu(r10[j]) + w11 * bfu(r11[j]);
                sv[p][j] = v;
                accp = fmaf(uu[j], v, accp);
            }
            part[p] = accp;
        }
        #pragma unroll
        for (int mk = 1; mk <= 16; mk <<= 1) {
            #pragma unroll
            for (int p = 0; p < 4; p++) part[p] += __shfl_xor(part[p], mk, 64);
        }
        float sc0 = part[0] * SCALE, sc1 = part[1] * SCALE;
        float sc2 = part[2] * SCALE, sc3 = part[3] * SCALE;
        float mx = fmaxf(fmaxf(sc0, sc1), fmaxf(sc2, sc3));
        float e0 = __expf(sc0 - mx), e1 = __expf(sc1 - mx);
        float e2 = __expf(sc2 - mx), e3 = __expf(sc3 - mx);
        float inv = 1.f / (e0 + e1 + e2 + e3);
        us8 o8;
        #pragma unroll
        for (int j = 0; j < 8; j++) {
            float mv = (e0 * sv[0][j] + e1 * sv[1][j]
                      + e2 * sv[2][j] + e3 * sv[3][j]) * inv;
            o8[j] = f2bf_rne(mv);
        }
        *(us8*)(A + t * 264 + c8) = o8;
    }
    for (int i = tid; i < 480; i += 256) {         // zero pad rows 49..63
        int row = 49 + (i >> 5);
        int cs = (i & 31) * 8;
        us8 z = {0, 0, 0, 0, 0, 0, 0, 0};
        *(us8*)(A + row * 264 + cs) = z;
    }
    __syncthreads();

    int lane = tid & 63;
    int wave = tid >> 6;
    int col  = lane & 15;
    int quad = lane >> 4;
    int cbase = wave * 64;

    f32x4 zero = {0.f, 0.f, 0.f, 0.f};
    f32x4 acc[4][4];
    #pragma unroll
    for (int i = 0; i < 4; i++)
        #pragma unroll
        for (int j = 0; j < 4; j++) acc[i][j] = zero;

    for (int ks = 0; ks < 8; ks++) {
        bf16x8 af[4];
        #pragma unroll
        for (int rt = 0; rt < 4; rt++)
            af[rt] = *(const bf16x8*)(A + (rt * 16 + col) * 264 + ks * 32 + quad * 8);
        #pragma unroll
        for (int ct = 0; ct < 4; ct++) {
            size_t bo = (size_t)(cbase + ct * 16 + col) * 256 + ks * 32 + quad * 8;
            bf16x8 bh8 = *(const bf16x8*)(Mh + bo);
            bf16x8 bl8 = *(const bf16x8*)(Ml + bo);
            #pragma unroll
            for (int rt = 0; rt < 4; rt++) {
                acc[rt][ct] = __builtin_amdgcn_mfma_f32_16x16x32_bf16(af[rt], bh8, acc[rt][ct], 0, 0, 0);
                acc[rt][ct] = __builtin_amdgcn_mfma_f32_16x16x32_bf16(af[rt], bl8, acc[rt][ct], 0, 0, 0);
            }
        }
    }

    __syncthreads();
    float* ostage = (float*)ldsraw;   // [256][53]
    #pragma unroll
    for (int rt = 0; rt < 4; rt++) {
        #pragma unroll
        for (int ct = 0; ct < 4; ct++) {
            int c = cbase + ct * 16 + col;
            float bias = c_out[c];
            #pragma unroll
            for (int rr = 0; rr < 4; rr++) {
                int tt = rt * 16 + quad * 4 + rr;
                if (tt < 49) ostage[c * 53 + tt] = acc[rt][ct][rr] + bias;
            }
        }
    }
    __syncthreads();
    float* ob = out + (size_t)n * 12544;
    for (int k = 0; k < 49; k++) {
        int flat = k * 256 + tid;     // = c2*49 + t2
        int c2 = flat / 49;
        int t2 = flat - c2 * 49;
        ob[flat] = ostage[c2 * 53 + t2];
    }
}

struct MegaArgs {
    const float* features; const float* rois; const float* offs;
    const float* queries;  const float* w_proj; const float* b_proj;
    const float* in_proj_w; const float* in_proj_b;
    const float* out_proj_w; const float* out_proj_b;
    float* A_k; float* A_v; float* Qhat; float* cv;
    float* u;   float* c_out;
    unsigned short* Mh; unsigned short* Ml;
    unsigned short* feat_b;
    float* out;
};

// ============ ONE cooperative kernel. __launch_bounds__(256,2): 2 blocks/CU
// guaranteed (VGPR cap 256; LDS 2x54.3KB=108.5KB <= 160KB) so 512 blocks fit. ============
__global__ void __launch_bounds__(256, 2) mega(MegaArgs a) {
    __shared__ __align__(16) char ldsraw[54272];
    cg::grid_group grid = cg::this_grid();
    int tid = threadIdx.x;
    int bid = blockIdx.x;

    // phase 0a: pre1 (independent)
    for (int idx = bid * 256 + tid; idx < 143872; idx += 131072)
        dev_pre1(idx, a.w_proj, a.in_proj_w, a.in_proj_b, a.queries, a.b_proj,
                 a.A_k, a.A_v, a.Qhat, a.cv);

    // phase 0b: transpose (independent), 8 tiles/block
    for (int k = 0; k < 8; k++)
        dev_transpose_tile(ldsraw, bid * 8 + k, tid, a.features, a.feat_b);

    __threadfence();
    grid.sync();
    __threadfence();

    // phase 1: pre2
    dev_pre2(bid * 256 + tid, a.Qhat, a.A_k, a.A_v, a.out_proj_w, a.out_proj_b,
             a.cv, a.u, a.Mh, a.Ml, a.c_out);

    __threadfence();
    grid.sync();
    __threadfence();

    // phase 2: fused sample + MFMA GEMM, 1 block = 1 roi
    dev_sample_gemm(ldsraw, bid, tid, a.feat_b, a.rois, a.offs, a.u,
                    a.Mh, a.Ml, a.c_out, a.out);
}

// =================== fallback multi-kernel path (known-passing R3 chain) ===================
__global__ void k_pre1(const float* w_proj, const float* in_proj_w,
                       const float* in_proj_b, const float* queries,
                       const float* b_proj,
                       float* A_k, float* A_v, float* Qhat, float* cv) {
    dev_pre1(blockIdx.x * 256 + threadIdx.x, w_proj, in_proj_w, in_proj_b,
             queries, b_proj, A_k, A_v, Qhat, cv);
}
__global__ void k_pre2(const float* Qhat, const float* A_k, const float* A_v,
                       const float* out_proj_w, const float* out_proj_b,
                       const float* cv, float* u,
                       unsigned short* Mh, unsigned short* Ml, float* c_out) {
    dev_pre2(blockIdx.x * 256 + threadIdx.x, Qhat, A_k, A_v, out_proj_w,
             out_proj_b, cv, u, Mh, Ml, c_out);
}
__global__ void k_transpose(const float* features, unsigned short* feat_b) {
    __shared__ __align__(16) char ldsraw[16640];
    dev_transpose_tile(ldsraw, blockIdx.x, threadIdx.x, features, feat_b);
}
__global__ void __launch_bounds__(256) k_fused(const unsigned short* feat_b,
                                               const float* rois, const float* offs,
                                               const float* u,
                                               const unsigned short* Mh,
                                               const unsigned short* Ml,
                                               const float* c_out, float* out) {
    __shared__ __align__(16) char ldsraw[54272];
    dev_sample_gemm(ldsraw, blockIdx.x, threadIdx.x, feat_b, rois, offs, u,
                    Mh, Ml, c_out, out);
}

// ======= last-resort path if ws is too small for the NHWC feature copy =======
__global__ void sample_generic(const float* __restrict__ feat,
                               const float* __restrict__ rois,
                               const float* __restrict__ offs,
                               const float* __restrict__ u,
                               float* __restrict__ m_out) {
    __shared__ float red[4][4];
    int token = blockIdx.x;
    int n = token / 49;
    int t = token - n * 49;
    int h = t / 7;
    int w = t - h * 7;
    const float* r = rois + (size_t)n * 5;
    int bi   = (int)r[0];
    float x1 = r[1] * SPS - 0.5f;
    float y1 = r[2] * SPS - 0.5f;
    float rw = r[3] * SPS - 0.5f - x1;
    float rh = r[4] * SPS - 0.5f - y1;
    float bw = rw * (1.0f / 7.0f);
    float bh = rh * (1.0f / 7.0f);
    int c = threadIdx.x;
    const float* fb = feat + (size_t)bi * HW * C_DIM;
    float u_c = u[(size_t)t * 256 + c];
    float sv[4], part[4];
    #pragma unroll
    for (int p = 0; p < 4; p++) {
        float offw = offs[((p * 7 + h) * 7 + w) * 2 + 0];
        float offh = offs[((p * 7 + h) * 7 + w) * 2 + 1];
        float y = y1 + ((float)h + 0.5f) * bh + GAMMA * rh * offh;
        float x = x1 + ((float)w + 0.5f) * bw + GAMMA * rw * offw;
        bool valid = (y > -1.0f) && (y < (float)H_DIM) && (x > -1.0f) && (x < (float)W_DIM);
        float yc = fminf(fmaxf(y, 0.f), 127.f);
        float xc = fminf(fmaxf(x, 0.f), 127.f);
        int y0i = (int)floorf(yc);
        int x0i = (int)floorf(xc);
        int y1i = min(y0i + 1, 127);
        int x1i = min(x0i + 1, 127);
        float ly = yc - (float)y0i, lx = xc - (float)x0i;
        float hy = 1.f - ly, hx = 1.f - lx;
        float v00 = fb[(size_t)c * HW + y0i * W_DIM + x0i];
        float v01 = fb[(size_t)c * HW + y0i * W_DIM + x1i];
        float v10 = fb[(size_t)c * HW + y1i * W_DIM + x0i];
        float v11 = fb[(size_t)c * HW + y1i * W_DIM + x1i];
        float v = hy * hx * v00 + hy * lx * v01 + ly * hx * v10 + ly * lx * v11;
        v = valid ? v : 0.f;
        sv[p] = v;
        part[p] = u_c * v;
    }
    #pragma unroll
    for (int o = 32; o >= 1; o >>= 1) {
        #pragma unroll
        for (int p = 0; p < 4; p++) part[p] += __shfl_down(part[p], o, 64);
    }
    int wv = threadIdx.x >> 6, lane = threadIdx.x & 63;
    if (lane == 0) {
        red[wv][0] = part[0]; red[wv][1] = part[1];
        red[wv][2] = part[2]; red[wv][3] = part[3];
    }
    __syncthreads();
    float sc0 = (red[0][0] + red[1][0] + red[2][0] + red[3][0]) * SCALE;
    float sc1 = (red[0][1] + red[1][1] + red[2][1] + red[3][1]) * SCALE;
    float sc2 = (red[0][2] + red[1][2] + red[2][2] + red[3][2]) * SCALE;
    float sc3 = (red[0][3] + red[1][3] + red[2][3] + red[3][3]) * SCALE;
    float mx = fmaxf(fmaxf(sc0, sc1), fmaxf(sc2, sc3));
    float e0 = __expf(sc0 - mx), e1 = __expf(sc1 - mx);
    float e2 = __expf(sc2 - mx), e3 = __expf(sc3 - mx);
    float inv = 1.f / (e0 + e1 + e2 + e3);
    m_out[(size_t)token * 256 + c] =
        (e0 * sv[0] + e1 * sv[1] + e2 * sv[2] + e3 * sv[3]) * inv;
}

// m (fp32 [n][t][d]) -> out via bf16-split MFMA, same math as dev_sample_gemm phase B
__global__ void __launch_bounds__(256) roi_gemm_m(const float* m,
                                                  const unsigned short* __restrict__ Mh,
                                                  const unsigned short* __restrict__ Ml,
                                                  const float* __restrict__ c_out,
                                                  float* out) {
    __shared__ __align__(16) char ldsraw[54272];
    unsigned short* A = (unsigned short*)ldsraw;
    int tid = threadIdx.x;
    int n = blockIdx.x;
    const float* mb = m + (size_t)n * 12544;
    for (int i = tid; i < 3136; i += 256) {
        float4 f = *(const float4*)(mb + (size_t)i * 4);
        int t = i >> 6;
        int d = (i & 63) * 4;
        unsigned short* dst = A + t * 264 + d;
        dst[0] = f2bf_rne(f.x); dst[1] = f2bf_rne(f.y);
        dst[2] = f2bf_rne(f.z); dst[3] = f2bf_rne(f.w);
    }
    for (int i = tid; i < 480; i += 256) {
        int row = 49 + (i >> 5);
        int cs = (i & 31) * 8;
        us8 z = {0,0,0,0,0,0,0,0};
        *(us8*)(A + row * 264 + cs) = z;
    }
    __syncthreads();
    int lane = tid & 63, wave = tid >> 6;
    int col = lane & 15, quad = lane >> 4;
    int cbase = wave * 64;
    f32x4 zero = {0.f,0.f,0.f,0.f};
    f32x4 acc[4][4];
    #pragma unroll
    for (int i = 0; i < 4; i++)
        #pragma unroll
        for (int j = 0; j < 4; j++) acc[i][j] = zero;
    for (int ks = 0; ks < 8; ks++) {
        bf16x8 af[4];
        #pragma unroll
        for (int rt = 0; rt < 4; rt++)
            af[rt] = *(const bf16x8*)(A + (rt * 16 + col) * 264 + ks * 32 + quad * 8);
        #pragma unroll
        for (int ct = 0; ct < 4; ct++) {
            size_t bo = (size_t)(cbase + ct * 16 + col) * 256 + ks * 32 + quad * 8;
            bf16x8 bh8 = *(const bf16x8*)(Mh + bo);
            bf16x8 bl8 = *(const bf16x8*)(Ml + bo);
            #pragma unroll
            for (int rt = 0; rt < 4; rt++) {
                acc[rt][ct] = __builtin_amdgcn_mfma_f32_16x16x32_bf16(af[rt], bh8, acc[rt][ct], 0, 0, 0);
                acc[rt][ct] = __builtin_amdgcn_mfma_f32_16x16x32_bf16(af[rt], bl8, acc[rt][ct], 0, 0, 0);
            }
        }
    }
    __syncthreads();
    float* ostage = (float*)ldsraw;
    #pragma unroll
    for (int rt = 0; rt < 4; rt++) {
        #pragma unroll
        for (int ct = 0; ct < 4; ct++) {
            int c = cbase + ct * 16 + col;
            float bias = c_out[c];
            #pragma unroll
            for (int rr = 0; rr < 4; rr++) {
                int tt = rt * 16 + quad * 4 + rr;
                if (tt < 49) ostage[c * 53 + tt] = acc[rt][ct][rr] + bias;
            }
        }
    }
    __syncthreads();
    float* ob = out + (size_t)n * 12544;
    for (int k = 0; k < 49; k++) {
        int flat = k * 256 + tid;
        int c2 = flat / 49;
        int t2 = flat - c2 * 49;
        ob[flat] = ostage[c2 * 53 + t2];
    }
}

extern "C" void kernel_launch(void* const* d_in, const int* in_sizes, int n_in,
                              void* d_out, int out_size, void* d_ws, size_t ws_size,
                              hipStream_t stream) {
    (void)in_sizes; (void)n_in; (void)out_size;
    const float* features   = (const float*)d_in[0];
    const float* rois       = (const float*)d_in[1];
    const float* offs       = (const float*)d_in[2];
    const float* queries    = (const float*)d_in[3];
    const float* w_proj     = (const float*)d_in[4];
    const float* b_proj     = (const float*)d_in[5];
    const float* in_proj_w  = (const float*)d_in[6];
    const float* in_proj_b  = (const float*)d_in[7];
    const float* out_proj_w = (const float*)d_in[8];
    const float* out_proj_b = (const float*)d_in[9];
    float* out = (float*)d_out;
    float* ws  = (float*)d_ws;

    // workspace layout (float units)
    float* A_k   = ws;                    // 65536
    float* A_v   = A_k  + 65536;          // 65536
    float* Qhat  = A_v  + 65536;          // 12544
    float* cv    = Qhat + 12544;          // 256
    float* u     = cv   + 256;            // 12544
    float* c_out = u    + 12544;          // 256   -> ends at 156672
    unsigned short* Mh = (unsigned short*)(ws + 156672);  // 65536 shorts
    unsigned short* Ml = (unsigned short*)(ws + 189440);  // 65536 shorts
    unsigned short* feat_b = (unsigned short*)(ws + 222208); // 16777216 shorts
    float* m_fb = ws + 222208;            // last-resort m buffer (overlaps feat_b)

    size_t needT = ((size_t)222208 + (size_t)8388608) * 4;
    size_t needF = ((size_t)222208 + (size_t)TOKENS * 256) * 4;
    bool useT = ws_size >= needT;

    if (useT) {
        // gate the cooperative path on actual achievable occupancy
        int nb = 0;
        hipError_t oe = hipOccupancyMaxActiveBlocksPerMultiprocessor(&nb, mega, 256, 0);
        bool coop = (oe == hipSuccess) && (nb >= 2);

        if (coop) {
            MegaArgs ha;
            ha.features = features; ha.rois = rois; ha.offs = offs; ha.queries = queries;
            ha.w_proj = w_proj; ha.b_proj = b_proj; ha.in_proj_w = in_proj_w;
            ha.in_proj_b = in_proj_b; ha.out_proj_w = out_proj_w; ha.out_proj_b = out_proj_b;
            ha.A_k = A_k; ha.A_v = A_v; ha.Qhat = Qhat; ha.cv = cv;
            ha.u = u; ha.c_out = c_out; ha.Mh = Mh; ha.Ml = Ml;
            ha.feat_b = feat_b; ha.out = out;
            void* kp[] = { &ha };
            hipError_t le = hipLaunchCooperativeKernel(
                reinterpret_cast<void*>(mega), dim3(N_ROIS), dim3(256), kp, 0, stream);
            if (le == hipSuccess) return;
            (void)hipGetLastError();   // clear; fall through to multi-kernel path
        }
        k_pre1<<<562, 256, 0, stream>>>(w_proj, in_proj_w, in_proj_b, queries,
                                        b_proj, A_k, A_v, Qhat, cv);
        k_transpose<<<4096, 256, 0, stream>>>(features, feat_b);
        k_pre2<<<306, 256, 0, stream>>>(Qhat, A_k, A_v, out_proj_w, out_proj_b,
                                        cv, u, Mh, Ml, c_out);
        k_fused<<<N_ROIS, 256, 0, stream>>>(feat_b, rois, offs, u, Mh, Ml, c_out, out);
    } else {
        k_pre1<<<562, 256, 0, stream>>>(w_proj, in_proj_w, in_proj_b, queries,
                                        b_proj, A_k, A_v, Qhat, cv);
        k_pre2<<<306, 256, 0, stream>>>(Qhat, A_k, A_v, out_proj_w, out_proj_b,
                                        cv, u, Mh, Ml, c_out);
        float* m = (ws_size >= needF) ? m_fb : out;
        sample_generic<<<TOKENS, 256, 0, stream>>>(features, rois, offs, u, m);
        roi_gemm_m<<<N_ROIS, 256, 0, stream>>>(m, Mh, Ml, c_out, out);
    }
}

// Round 6
// 186.987 us; speedup vs baseline: 1.1900x; 1.1900x over previous
//
#include <hip/hip_runtime.h>
#include <math.h>

#define C_DIM 256
#define H_DIM 128
#define W_DIM 128
#define HW (H_DIM*W_DIM)
#define N_ROIS 512
#define TOKENS (N_ROIS*49)
#define SPS 0.0625f             // spatial scale
#define GAMMA 0.1f
#define SCALE 0.0625f           // d^-0.5 = 1/16

typedef __attribute__((ext_vector_type(8))) short bf16x8;
typedef __attribute__((ext_vector_type(4))) float f32x4;
typedef __attribute__((ext_vector_type(8))) unsigned short us8;

__device__ inline unsigned short f2bf_rne(float f) {
    unsigned int b = __float_as_uint(f);
    b += 0x7fffu + ((b >> 16) & 1u);
    return (unsigned short)(b >> 16);
}
__device__ inline float bfu(unsigned short u) {
    return __uint_as_float(((unsigned int)u) << 16);
}

// pre1 body: A_k = Wk@W_proj, A_v = Wv@W_proj, Qhat = queries@Wq.T + bq, cv = Wv@b_proj + bv
__device__ inline void pre1_body(int idx,
                                 const float* __restrict__ w_proj,
                                 const float* __restrict__ in_proj_w,
                                 const float* __restrict__ in_proj_b,
                                 const float* __restrict__ queries,
                                 const float* __restrict__ b_proj,
                                 float* __restrict__ A_k, float* __restrict__ A_v,
                                 float* __restrict__ Qhat, float* __restrict__ cv) {
    if (idx < 65536) {
        int i = idx >> 8, j = idx & 255;
        const float* wk = in_proj_w + (size_t)(256 + i) * 256;
        float s = 0.f;
        for (int t = 0; t < 256; t++) s += wk[t] * w_proj[t * 256 + j];
        A_k[idx] = s;
    } else if (idx < 131072) {
        int e = idx - 65536;
        int i = e >> 8, j = e & 255;
        const float* wv = in_proj_w + (size_t)(512 + i) * 256;
        float s = 0.f;
        for (int t = 0; t < 256; t++) s += wv[t] * w_proj[t * 256 + j];
        A_v[e] = s;
    } else if (idx < 143616) {
        int e = idx - 131072;
        int s_ = e >> 8, i = e & 255;
        const float* q  = queries + (size_t)s_ * 256;
        const float* wq = in_proj_w + (size_t)i * 256;
        float s = in_proj_b[i];
        for (int t = 0; t < 256; t++) s += q[t] * wq[t];
        Qhat[e] = s;
    } else if (idx < 143872) {
        int i = idx - 143616;
        const float* wv = in_proj_w + (size_t)(512 + i) * 256;
        float s = in_proj_b[512 + i];
        for (int t = 0; t < 256; t++) s += wv[t] * b_proj[t];
        cv[i] = s;
    }
}

// ---------------- k_init: transpose (blocks 0..4095) + pre1 (blocks 4096..4657) ----------------
__global__ void __launch_bounds__(256) k_init(
        const float* __restrict__ features, unsigned short* __restrict__ feat_b,
        const float* __restrict__ w_proj, const float* __restrict__ in_proj_w,
        const float* __restrict__ in_proj_b, const float* __restrict__ queries,
        const float* __restrict__ b_proj,
        float* __restrict__ A_k, float* __restrict__ A_v,
        float* __restrict__ Qhat, float* __restrict__ cv) {
    int tid = threadIdx.x;
    int bid = blockIdx.x;
    if (bid < 4096) {
        // one 64ch x 64sp tile: NCHW fp32 -> NHWC bf16
        __shared__ float tile[64][65];
        int b   = bid >> 10;            // 4096 tiles: b(4) x c-grp(4) x s-grp(256)
        int rem = bid & 1023;
        int c0  = (rem >> 8) << 6;
        int s0  = (rem & 255) << 6;
        int sl = tid & 63, cw = tid >> 6;
        const float* fin = features + (size_t)b * C_DIM * HW;
        #pragma unroll
        for (int kk = 0; kk < 16; kk++) {
            int cl = cw + kk * 4;
            tile[cl][sl] = fin[(size_t)(c0 + cl) * HW + s0 + sl];
        }
        __syncthreads();
        unsigned short* fo = feat_b + (size_t)b * HW * C_DIM;
        #pragma unroll
        for (int kk = 0; kk < 16; kk++) {
            int sl2 = cw + kk * 4;
            fo[(size_t)(s0 + sl2) * C_DIM + c0 + sl] = f2bf_rne(tile[sl][sl2]);
        }
    } else {
        pre1_body((bid - 4096) * 256 + tid, w_proj, in_proj_w, in_proj_b,
                  queries, b_proj, A_k, A_v, Qhat, cv);
    }
}

// plain pre1 kernel (fallback path only)
__global__ void k_pre1(const float* __restrict__ w_proj,
                       const float* __restrict__ in_proj_w,
                       const float* __restrict__ in_proj_b,
                       const float* __restrict__ queries,
                       const float* __restrict__ b_proj,
                       float* __restrict__ A_k, float* __restrict__ A_v,
                       float* __restrict__ Qhat, float* __restrict__ cv) {
    pre1_body(blockIdx.x * 256 + threadIdx.x, w_proj, in_proj_w, in_proj_b,
              queries, b_proj, A_k, A_v, Qhat, cv);
}

// ---------------- k_pre2: u = Qhat@A_k, M = W_o@A_v (bf16 hi/lo), c_out = W_o@cv + b_o ----------------
__global__ void k_pre2(const float* __restrict__ Qhat,
                       const float* __restrict__ A_k,
                       const float* __restrict__ A_v,
                       const float* __restrict__ out_proj_w,
                       const float* __restrict__ out_proj_b,
                       const float* __restrict__ cv,
                       float* __restrict__ u,
                       unsigned short* __restrict__ Mh,
                       unsigned short* __restrict__ Ml,
                       float* __restrict__ c_out) {
    int idx = blockIdx.x * 256 + threadIdx.x;
    if (idx < 12544) {
        int s_ = idx >> 8, j = idx & 255;
        const float* qh = Qhat + (size_t)s_ * 256;
        float s = 0.f;
        for (int i = 0; i < 256; i++) s += qh[i] * A_k[i * 256 + j];
        u[idx] = s;
    } else if (idx < 78080) {
        int e = idx - 12544;
        int c = e >> 8, d = e & 255;
        const float* wo = out_proj_w + (size_t)c * 256;
        float s = 0.f;
        for (int i = 0; i < 256; i++) s += wo[i] * A_v[i * 256 + d];
        unsigned short hi = f2bf_rne(s);
        unsigned short lo = f2bf_rne(s - bfu(hi));
        Mh[(size_t)c * 256 + d] = hi;
        Ml[(size_t)c * 256 + d] = lo;
    } else if (idx < 78336) {
        int c = idx - 78080;
        const float* wo = out_proj_w + (size_t)c * 256;
        float s = out_proj_b[c];
        for (int i = 0; i < 256; i++) s += wo[i] * cv[i];
        c_out[c] = s;
    }
}

// ---------------- fused: sample + softmax-mix -> LDS bf16 A-tile -> MFMA GEMM ----------------
// R3-verbatim hot kernel (the <=42us version).
__global__ void __launch_bounds__(256) fused_sample_gemm(
        const unsigned short* __restrict__ feat_b,
        const float* __restrict__ rois,
        const float* __restrict__ offs,
        const float* __restrict__ u,
        const unsigned short* __restrict__ Mh,
        const unsigned short* __restrict__ Ml,
        const float* __restrict__ c_out,
        float* __restrict__ out) {
    __shared__ __align__(16) char ldsraw[54272];
    unsigned short* A = (unsigned short*)ldsraw;

    int tid = threadIdx.x;
    int n = blockIdx.x;

    const float* r = rois + (size_t)n * 5;
    int bi    = (int)r[0];
    float x1  = r[1] * SPS - 0.5f;
    float y1v = r[2] * SPS - 0.5f;
    float rw  = r[3] * SPS - 0.5f - x1;
    float rh  = r[4] * SPS - 0.5f - y1v;
    float bw  = rw * (1.0f / 7.0f);
    float bh  = rh * (1.0f / 7.0f);
    const unsigned short* fb = feat_b + (size_t)bi * HW * C_DIM;

    int lane32 = tid & 31;
    int halfw  = tid >> 5;
    int c8 = lane32 * 8;

    for (int t = halfw; t < 49; t += 8) {
        int hb = t / 7, wb = t - hb * 7;
        const float* up = u + (size_t)t * 256 + c8;
        float uu[8];
        *(float4*)uu       = *(const float4*)up;
        *(float4*)(uu + 4) = *(const float4*)(up + 4);

        float sv[4][8];
        float part[4];
        #pragma unroll
        for (int p = 0; p < 4; p++) {
            float offw = offs[((p * 7 + hb) * 7 + wb) * 2 + 0];
            float offh = offs[((p * 7 + hb) * 7 + wb) * 2 + 1];
            float y = y1v + ((float)hb + 0.5f) * bh + GAMMA * rh * offh;
            float x = x1  + ((float)wb + 0.5f) * bw + GAMMA * rw * offw;
            bool valid = (y > -1.0f) && (y < 128.0f) && (x > -1.0f) && (x < 128.0f);
            float yc = fminf(fmaxf(y, 0.f), 127.f);
            float xc = fminf(fmaxf(x, 0.f), 127.f);
            int y0i = (int)yc, x0i = (int)xc;       // >=0: trunc == floor
            int y1i = min(y0i + 1, 127), x1i = min(x0i + 1, 127);
            float ly = yc - (float)y0i, lx = xc - (float)x0i;
            float hy = 1.f - ly, hx = 1.f - lx;
            float w00 = hy * hx, w01 = hy * lx, w10 = ly * hx, w11 = ly * lx;
            if (!valid) { w00 = 0.f; w01 = 0.f; w10 = 0.f; w11 = 0.f; }
            us8 r00 = *(const us8*)(fb + (size_t)(y0i * W_DIM + x0i) * 256 + c8);
            us8 r01 = *(const us8*)(fb + (size_t)(y0i * W_DIM + x1i) * 256 + c8);
            us8 r10 = *(const us8*)(fb + (size_t)(y1i * W_DIM + x0i) * 256 + c8);
            us8 r11 = *(const us8*)(fb + (size_t)(y1i * W_DIM + x1i) * 256 + c8);
            float accp = 0.f;
            #pragma unroll
            for (int j = 0; j < 8; j++) {
                float v = w00 * bfu(r00[j]) + w01 * bfu(r01[j])
                        + w10 * bfu(r10[j]) + w11 * bfu(r11[j]);
                sv[p][j] = v;
                accp = fmaf(uu[j], v, accp);
            }
            part[p] = accp;
        }
        #pragma unroll
        for (int mk = 1; mk <= 16; mk <<= 1) {
            #pragma unroll
            for (int p = 0; p < 4; p++) part[p] += __shfl_xor(part[p], mk, 64);
        }
        float sc0 = part[0] * SCALE, sc1 = part[1] * SCALE;
        float sc2 = part[2] * SCALE, sc3 = part[3] * SCALE;
        float mx = fmaxf(fmaxf(sc0, sc1), fmaxf(sc2, sc3));
        float e0 = __expf(sc0 - mx), e1 = __expf(sc1 - mx);
        float e2 = __expf(sc2 - mx), e3 = __expf(sc3 - mx);
        float inv = 1.f / (e0 + e1 + e2 + e3);
        us8 o8;
        #pragma unroll
        for (int j = 0; j < 8; j++) {
            float mv = (e0 * sv[0][j] + e1 * sv[1][j]
                      + e2 * sv[2][j] + e3 * sv[3][j]) * inv;
            o8[j] = f2bf_rne(mv);
        }
        *(us8*)(A + t * 264 + c8) = o8;
    }
    for (int i = tid; i < 480; i += 256) {         // zero pad rows 49..63
        int row = 49 + (i >> 5);
        int cs = (i & 31) * 8;
        us8 z = {0, 0, 0, 0, 0, 0, 0, 0};
        *(us8*)(A + row * 264 + cs) = z;
    }
    __syncthreads();

    int lane = tid & 63;
    int wave = tid >> 6;
    int col  = lane & 15;
    int quad = lane >> 4;
    int cbase = wave * 64;

    f32x4 zero = {0.f, 0.f, 0.f, 0.f};
    f32x4 acc[4][4];
    #pragma unroll
    for (int i = 0; i < 4; i++)
        #pragma unroll
        for (int j = 0; j < 4; j++) acc[i][j] = zero;

    for (int ks = 0; ks < 8; ks++) {
        bf16x8 af[4];
        #pragma unroll
        for (int rt = 0; rt < 4; rt++)
            af[rt] = *(const bf16x8*)(A + (rt * 16 + col) * 264 + ks * 32 + quad * 8);
        #pragma unroll
        for (int ct = 0; ct < 4; ct++) {
            size_t bo = (size_t)(cbase + ct * 16 + col) * 256 + ks * 32 + quad * 8;
            bf16x8 bh8 = *(const bf16x8*)(Mh + bo);
            bf16x8 bl8 = *(const bf16x8*)(Ml + bo);
            #pragma unroll
            for (int rt = 0; rt < 4; rt++) {
                acc[rt][ct] = __builtin_amdgcn_mfma_f32_16x16x32_bf16(af[rt], bh8, acc[rt][ct], 0, 0, 0);
                acc[rt][ct] = __builtin_amdgcn_mfma_f32_16x16x32_bf16(af[rt], bl8, acc[rt][ct], 0, 0, 0);
            }
        }
    }

    __syncthreads();
    float* ostage = (float*)ldsraw;   // [256][53]
    #pragma unroll
    for (int rt = 0; rt < 4; rt++) {
        #pragma unroll
        for (int ct = 0; ct < 4; ct++) {
            int c = cbase + ct * 16 + col;
            float bias = c_out[c];
            #pragma unroll
            for (int rr = 0; rr < 4; rr++) {
                int tt = rt * 16 + quad * 4 + rr;
                if (tt < 49) ostage[c * 53 + tt] = acc[rt][ct][rr] + bias;
            }
        }
    }
    __syncthreads();
    float* ob = out + (size_t)n * 12544;
    for (int k = 0; k < 49; k++) {
        int flat = k * 256 + tid;     // = c2*49 + t2
        int c2 = flat / 49;
        int t2 = flat - c2 * 49;
        ob[flat] = ostage[c2 * 53 + t2];
    }
}

// ======= last-resort path if ws is too small for the NHWC feature copy =======
__global__ void sample_generic(const float* __restrict__ feat,
                               const float* __restrict__ rois,
                               const float* __restrict__ offs,
                               const float* __restrict__ u,
                               float* __restrict__ m_out) {
    __shared__ float red[4][4];
    int token = blockIdx.x;
    int n = token / 49;
    int t = token - n * 49;
    int h = t / 7;
    int w = t - h * 7;
    const float* r = rois + (size_t)n * 5;
    int bi   = (int)r[0];
    float x1 = r[1] * SPS - 0.5f;
    float y1 = r[2] * SPS - 0.5f;
    float rw = r[3] * SPS - 0.5f - x1;
    float rh = r[4] * SPS - 0.5f - y1;
    float bw = rw * (1.0f / 7.0f);
    float bh = rh * (1.0f / 7.0f);
    int c = threadIdx.x;
    const float* fb = feat + (size_t)bi * HW * C_DIM;
    float u_c = u[(size_t)t * 256 + c];
    float sv[4], part[4];
    #pragma unroll
    for (int p = 0; p < 4; p++) {
        float offw = offs[((p * 7 + h) * 7 + w) * 2 + 0];
        float offh = offs[((p * 7 + h) * 7 + w) * 2 + 1];
        float y = y1 + ((float)h + 0.5f) * bh + GAMMA * rh * offh;
        float x = x1 + ((float)w + 0.5f) * bw + GAMMA * rw * offw;
        bool valid = (y > -1.0f) && (y < (float)H_DIM) && (x > -1.0f) && (x < (float)W_DIM);
        float yc = fminf(fmaxf(y, 0.f), 127.f);
        float xc = fminf(fmaxf(x, 0.f), 127.f);
        int y0i = (int)floorf(yc);
        int x0i = (int)floorf(xc);
        int y1i = min(y0i + 1, 127);
        int x1i = min(x0i + 1, 127);
        float ly = yc - (float)y0i, lx = xc - (float)x0i;
        float hy = 1.f - ly, hx = 1.f - lx;
        float v00 = fb[(size_t)c * HW + y0i * W_DIM + x0i];
        float v01 = fb[(size_t)c * HW + y0i * W_DIM + x1i];
        float v10 = fb[(size_t)c * HW + y1i * W_DIM + x0i];
        float v11 = fb[(size_t)c * HW + y1i * W_DIM + x1i];
        float v = hy * hx * v00 + hy * lx * v01 + ly * hx * v10 + ly * lx * v11;
        v = valid ? v : 0.f;
        sv[p] = v;
        part[p] = u_c * v;
    }
    #pragma unroll
    for (int o = 32; o >= 1; o >>= 1) {
        #pragma unroll
        for (int p = 0; p < 4; p++) part[p] += __shfl_down(part[p], o, 64);
    }
    int wv = threadIdx.x >> 6, lane = threadIdx.x & 63;
    if (lane == 0) {
        red[wv][0] = part[0]; red[wv][1] = part[1];
        red[wv][2] = part[2]; red[wv][3] = part[3];
    }
    __syncthreads();
    float sc0 = (red[0][0] + red[1][0] + red[2][0] + red[3][0]) * SCALE;
    float sc1 = (red[0][1] + red[1][1] + red[2][1] + red[3][1]) * SCALE;
    float sc2 = (red[0][2] + red[1][2] + red[2][2] + red[3][2]) * SCALE;
    float sc3 = (red[0][3] + red[1][3] + red[2][3] + red[3][3]) * SCALE;
    float mx = fmaxf(fmaxf(sc0, sc1), fmaxf(sc2, sc3));
    float e0 = __expf(sc0 - mx), e1 = __expf(sc1 - mx);
    float e2 = __expf(sc2 - mx), e3 = __expf(sc3 - mx);
    float inv = 1.f / (e0 + e1 + e2 + e3);
    m_out[(size_t)token * 256 + c] =
        (e0 * sv[0] + e1 * sv[1] + e2 * sv[2] + e3 * sv[3]) * inv;
}

__global__ void __launch_bounds__(256) roi_gemm_m(const float* __restrict__ m,
                                                  const unsigned short* __restrict__ Mh,
                                                  const unsigned short* __restrict__ Ml,
                                                  const float* __restrict__ c_out,
                                                  float* __restrict__ out) {
    __shared__ __align__(16) char ldsraw[54272];
    unsigned short* A = (unsigned short*)ldsraw;
    int tid = threadIdx.x;
    int n = blockIdx.x;
    const float* mb = m + (size_t)n * 12544;
    for (int i = tid; i < 3136; i += 256) {
        float4 f = *(const float4*)(mb + (size_t)i * 4);
        int t = i >> 6;
        int d = (i & 63) * 4;
        unsigned short* dst = A + t * 264 + d;
        dst[0] = f2bf_rne(f.x); dst[1] = f2bf_rne(f.y);
        dst[2] = f2bf_rne(f.z); dst[3] = f2bf_rne(f.w);
    }
    for (int i = tid; i < 480; i += 256) {
        int row = 49 + (i >> 5);
        int cs = (i & 31) * 8;
        us8 z = {0,0,0,0,0,0,0,0};
        *(us8*)(A + row * 264 + cs) = z;
    }
    __syncthreads();
    int lane = tid & 63, wave = tid >> 6;
    int col = lane & 15, quad = lane >> 4;
    int cbase = wave * 64;
    f32x4 zero = {0.f,0.f,0.f,0.f};
    f32x4 acc[4][4];
    #pragma unroll
    for (int i = 0; i < 4; i++)
        #pragma unroll
        for (int j = 0; j < 4; j++) acc[i][j] = zero;
    for (int ks = 0; ks < 8; ks++) {
        bf16x8 af[4];
        #pragma unroll
        for (int rt = 0; rt < 4; rt++)
            af[rt] = *(const bf16x8*)(A + (rt * 16 + col) * 264 + ks * 32 + quad * 8);
        #pragma unroll
        for (int ct = 0; ct < 4; ct++) {
            size_t bo = (size_t)(cbase + ct * 16 + col) * 256 + ks * 32 + quad * 8;
            bf16x8 bh8 = *(const bf16x8*)(Mh + bo);
            bf16x8 bl8 = *(const bf16x8*)(Ml + bo);
            #pragma unroll
            for (int rt = 0; rt < 4; rt++) {
                acc[rt][ct] = __builtin_amdgcn_mfma_f32_16x16x32_bf16(af[rt], bh8, acc[rt][ct], 0, 0, 0);
                acc[rt][ct] = __builtin_amdgcn_mfma_f32_16x16x32_bf16(af[rt], bl8, acc[rt][ct], 0, 0, 0);
            }
        }
    }
    __syncthreads();
    float* ostage = (float*)ldsraw;
    #pragma unroll
    for (int rt = 0; rt < 4; rt++) {
        #pragma unroll
        for (int ct = 0; ct < 4; ct++) {
            int c = cbase + ct * 16 + col;
            float bias = c_out[c];
            #pragma unroll
            for (int rr = 0; rr < 4; rr++) {
                int tt = rt * 16 + quad * 4 + rr;
                if (tt < 49) ostage[c * 53 + tt] = acc[rt][ct][rr] + bias;
            }
        }
    }
    __syncthreads();
    float* ob = out + (size_t)n * 12544;
    for (int k = 0; k < 49; k++) {
        int flat = k * 256 + tid;
        int c2 = flat / 49;
        int t2 = flat - c2 * 49;
        ob[flat] = ostage[c2 * 53 + t2];
    }
}

extern "C" void kernel_launch(void* const* d_in, const int* in_sizes, int n_in,
                              void* d_out, int out_size, void* d_ws, size_t ws_size,
                              hipStream_t stream) {
    (void)in_sizes; (void)n_in; (void)out_size;
    const float* features   = (const float*)d_in[0];
    const float* rois       = (const float*)d_in[1];
    const float* offs       = (const float*)d_in[2];
    const float* queries    = (const float*)d_in[3];
    const float* w_proj     = (const float*)d_in[4];
    const float* b_proj     = (const float*)d_in[5];
    const float* in_proj_w  = (const float*)d_in[6];
    const float* in_proj_b  = (const float*)d_in[7];
    const float* out_proj_w = (const float*)d_in[8];
    const float* out_proj_b = (const float*)d_in[9];
    float* out = (float*)d_out;
    float* ws  = (float*)d_ws;

    float* A_k   = ws;                    // 65536
    float* A_v   = A_k  + 65536;          // 65536
    float* Qhat  = A_v  + 65536;          // 12544
    float* cv    = Qhat + 12544;          // 256
    float* u     = cv   + 256;            // 12544
    float* c_out = u    + 12544;          // 256   -> ends at 156672
    unsigned short* Mh = (unsigned short*)(ws + 156672);  // 65536 shorts
    unsigned short* Ml = (unsigned short*)(ws + 189440);  // 65536 shorts
    unsigned short* feat_b = (unsigned short*)(ws + 222208); // 16777216 shorts
    float* m_fb = ws + 222208;            // last-resort m buffer (overlaps feat_b)

    size_t needT = ((size_t)222208 + (size_t)8388608) * 4;
    size_t needF = ((size_t)222208 + (size_t)TOKENS * 256) * 4;
    bool useT = ws_size >= needT;

    if (useT) {
        k_init<<<4096 + 562, 256, 0, stream>>>(features, feat_b,
                                               w_proj, in_proj_w, in_proj_b,
                                               queries, b_proj,
                                               A_k, A_v, Qhat, cv);
        k_pre2<<<306, 256, 0, stream>>>(Qhat, A_k, A_v, out_proj_w, out_proj_b,
                                        cv, u, Mh, Ml, c_out);
        fused_sample_gemm<<<N_ROIS, 256, 0, stream>>>(feat_b, rois, offs, u,
                                                      Mh, Ml, c_out, out);
    } else {
        k_pre1<<<562, 256, 0, stream>>>(w_proj, in_proj_w, in_proj_b,
                                        queries, b_proj, A_k, A_v, Qhat, cv);
        k_pre2<<<306, 256, 0, stream>>>(Qhat, A_k, A_v, out_proj_w, out_proj_b,
                                        cv, u, Mh, Ml, c_out);
        float* m = (ws_size >= needF) ? m_fb : out;
        sample_generic<<<TOKENS, 256, 0, stream>>>(features, rois, offs, u, m);
        roi_gemm_m<<<N_ROIS, 256, 0, stream>>>(m, Mh, Ml, c_out, out);
    }
}

// Round 7
// 183.391 us; speedup vs baseline: 1.2133x; 1.0196x over previous
//
#include <hip/hip_runtime.h>
#include <math.h>

#define C_DIM 256
#define H_DIM 128
#define W_DIM 128
#define HW (H_DIM*W_DIM)
#define N_ROIS 512
#define TOKENS (N_ROIS*49)
#define SPS 0.0625f             // spatial scale
#define GAMMA 0.1f
#define SCALE 0.0625f           // d^-0.5 = 1/16

typedef __attribute__((ext_vector_type(8))) short bf16x8;
typedef __attribute__((ext_vector_type(4))) float f32x4;
typedef __attribute__((ext_vector_type(8))) unsigned short us8;

__device__ inline unsigned short f2bf_rne(float f) {
    unsigned int b = __float_as_uint(f);
    b += 0x7fffu + ((b >> 16) & 1u);
    return (unsigned short)(b >> 16);
}
__device__ inline float bfu(unsigned short u) {
    return __uint_as_float(((unsigned int)u) << 16);
}

// pre1 body: A_k = Wk@W_proj, A_v = Wv@W_proj, Qhat = queries@Wq.T + bq, cv = Wv@b_proj + bv
__device__ inline void pre1_body(int idx,
                                 const float* __restrict__ w_proj,
                                 const float* __restrict__ in_proj_w,
                                 const float* __restrict__ in_proj_b,
                                 const float* __restrict__ queries,
                                 const float* __restrict__ b_proj,
                                 float* __restrict__ A_k, float* __restrict__ A_v,
                                 float* __restrict__ Qhat, float* __restrict__ cv) {
    if (idx < 65536) {
        int i = idx >> 8, j = idx & 255;
        const float* wk = in_proj_w + (size_t)(256 + i) * 256;
        float s = 0.f;
        for (int t = 0; t < 256; t++) s += wk[t] * w_proj[t * 256 + j];
        A_k[idx] = s;
    } else if (idx < 131072) {
        int e = idx - 65536;
        int i = e >> 8, j = e & 255;
        const float* wv = in_proj_w + (size_t)(512 + i) * 256;
        float s = 0.f;
        for (int t = 0; t < 256; t++) s += wv[t] * w_proj[t * 256 + j];
        A_v[e] = s;
    } else if (idx < 143616) {
        int e = idx - 131072;
        int s_ = e >> 8, i = e & 255;
        const float* q  = queries + (size_t)s_ * 256;
        const float* wq = in_proj_w + (size_t)i * 256;
        float s = in_proj_b[i];
        for (int t = 0; t < 256; t++) s += q[t] * wq[t];
        Qhat[e] = s;
    } else if (idx < 143872) {
        int i = idx - 143616;
        const float* wv = in_proj_w + (size_t)(512 + i) * 256;
        float s = in_proj_b[512 + i];
        for (int t = 0; t < 256; t++) s += wv[t] * b_proj[t];
        cv[i] = s;
    }
}

// ---------------- k_init: transpose (blocks 0..4095) + pre1 (blocks 4096..4657) ----------------
// Transpose store side widened to 16 B/lane (us8 of 8 channels per store).
__global__ void __launch_bounds__(256) k_init(
        const float* __restrict__ features, unsigned short* __restrict__ feat_b,
        const float* __restrict__ w_proj, const float* __restrict__ in_proj_w,
        const float* __restrict__ in_proj_b, const float* __restrict__ queries,
        const float* __restrict__ b_proj,
        float* __restrict__ A_k, float* __restrict__ A_v,
        float* __restrict__ Qhat, float* __restrict__ cv) {
    int tid = threadIdx.x;
    int bid = blockIdx.x;
    if (bid < 4096) {
        // one 64ch x 64sp tile: NCHW fp32 -> NHWC bf16
        __shared__ float tile[64][65];
        int b   = bid >> 10;            // 4096 tiles: b(4) x c-grp(4) x s-grp(256)
        int rem = bid & 1023;
        int c0  = (rem >> 8) << 6;
        int s0  = (rem & 255) << 6;
        int sl = tid & 63, cw = tid >> 6;
        const float* fin = features + (size_t)b * C_DIM * HW;
        #pragma unroll
        for (int kk = 0; kk < 16; kk++) {
            int cl = cw + kk * 4;
            tile[cl][sl] = fin[(size_t)(c0 + cl) * HW + s0 + sl];
        }
        __syncthreads();
        unsigned short* fo = feat_b + (size_t)b * HW * C_DIM;
        int g = tid & 7;                // channel group (8 ch)
        int pxb = tid >> 3;             // pixel 0..31 (+32 on second pass)
        #pragma unroll
        for (int kk = 0; kk < 2; kk++) {
            int px = pxb + kk * 32;
            us8 o8;
            #pragma unroll
            for (int j = 0; j < 8; j++)
                o8[j] = f2bf_rne(tile[g * 8 + j][px]);   // bank=(g*8+j+px)%32: 2-way, free
            *(us8*)(fo + (size_t)(s0 + px) * C_DIM + c0 + g * 8) = o8;
        }
    } else {
        pre1_body((bid - 4096) * 256 + tid, w_proj, in_proj_w, in_proj_b,
                  queries, b_proj, A_k, A_v, Qhat, cv);
    }
}

// plain pre1 kernel (fallback path only)
__global__ void k_pre1(const float* __restrict__ w_proj,
                       const float* __restrict__ in_proj_w,
                       const float* __restrict__ in_proj_b,
                       const float* __restrict__ queries,
                       const float* __restrict__ b_proj,
                       float* __restrict__ A_k, float* __restrict__ A_v,
                       float* __restrict__ Qhat, float* __restrict__ cv) {
    pre1_body(blockIdx.x * 256 + threadIdx.x, w_proj, in_proj_w, in_proj_b,
              queries, b_proj, A_k, A_v, Qhat, cv);
}

// ---------------- k_pre2: u = Qhat@A_k, M = W_o@A_v (bf16 hi/lo), c_out = W_o@cv + b_o ----------------
__global__ void k_pre2(const float* __restrict__ Qhat,
                       const float* __restrict__ A_k,
                       const float* __restrict__ A_v,
                       const float* __restrict__ out_proj_w,
                       const float* __restrict__ out_proj_b,
                       const float* __restrict__ cv,
                       float* __restrict__ u,
                       unsigned short* __restrict__ Mh,
                       unsigned short* __restrict__ Ml,
                       float* __restrict__ c_out) {
    int idx = blockIdx.x * 256 + threadIdx.x;
    if (idx < 12544) {
        int s_ = idx >> 8, j = idx & 255;
        const float* qh = Qhat + (size_t)s_ * 256;
        float s = 0.f;
        for (int i = 0; i < 256; i++) s += qh[i] * A_k[i * 256 + j];
        u[idx] = s;
    } else if (idx < 78080) {
        int e = idx - 12544;
        int c = e >> 8, d = e & 255;
        const float* wo = out_proj_w + (size_t)c * 256;
        float s = 0.f;
        for (int i = 0; i < 256; i++) s += wo[i] * A_v[i * 256 + d];
        unsigned short hi = f2bf_rne(s);
        unsigned short lo = f2bf_rne(s - bfu(hi));
        Mh[(size_t)c * 256 + d] = hi;
        Ml[(size_t)c * 256 + d] = lo;
    } else if (idx < 78336) {
        int c = idx - 78080;
        const float* wo = out_proj_w + (size_t)c * 256;
        float s = out_proj_b[c];
        for (int i = 0; i < 256; i++) s += wo[i] * cv[i];
        c_out[c] = s;
    }
}

// ---------------- fused: sample + softmax-mix -> LDS bf16 A-tile -> MFMA GEMM ----------------
// 512 threads/block: 16 half-wave sampling chains (3.1 serial tokens each vs 6.2
// at 256 threads) -> halves the latency-bound sampling critical path.
// __launch_bounds__(512,4): VGPR<=128 so 2 blocks/CU stay co-resident.
__global__ void __launch_bounds__(512, 4) fused_sample_gemm(
        const unsigned short* __restrict__ feat_b,
        const float* __restrict__ rois,
        const float* __restrict__ offs,
        const float* __restrict__ u,
        const unsigned short* __restrict__ Mh,
        const unsigned short* __restrict__ Ml,
        const float* __restrict__ c_out,
        float* __restrict__ out) {
    __shared__ __align__(16) char ldsraw[54272];
    unsigned short* A = (unsigned short*)ldsraw;

    int tid = threadIdx.x;
    int n = blockIdx.x;

    const float* r = rois + (size_t)n * 5;
    int bi    = (int)r[0];
    float x1  = r[1] * SPS - 0.5f;
    float y1v = r[2] * SPS - 0.5f;
    float rw  = r[3] * SPS - 0.5f - x1;
    float rh  = r[4] * SPS - 0.5f - y1v;
    float bw  = rw * (1.0f / 7.0f);
    float bh  = rh * (1.0f / 7.0f);
    const unsigned short* fb = feat_b + (size_t)bi * HW * C_DIM;

    int lane32 = tid & 31;
    int halfw  = tid >> 5;           // 0..15
    int c8 = lane32 * 8;

    for (int t = halfw; t < 49; t += 16) {
        int hb = t / 7, wb = t - hb * 7;
        const float* up = u + (size_t)t * 256 + c8;
        float uu[8];
        *(float4*)uu       = *(const float4*)up;
        *(float4*)(uu + 4) = *(const float4*)(up + 4);

        float sv[4][8];
        float part[4];
        #pragma unroll
        for (int p = 0; p < 4; p++) {
            float offw = offs[((p * 7 + hb) * 7 + wb) * 2 + 0];
            float offh = offs[((p * 7 + hb) * 7 + wb) * 2 + 1];
            float y = y1v + ((float)hb + 0.5f) * bh + GAMMA * rh * offh;
            float x = x1  + ((float)wb + 0.5f) * bw + GAMMA * rw * offw;
            bool valid = (y > -1.0f) && (y < 128.0f) && (x > -1.0f) && (x < 128.0f);
            float yc = fminf(fmaxf(y, 0.f), 127.f);
            float xc = fminf(fmaxf(x, 0.f), 127.f);
            int y0i = (int)yc, x0i = (int)xc;       // >=0: trunc == floor
            int y1i = min(y0i + 1, 127), x1i = min(x0i + 1, 127);
            float ly = yc - (float)y0i, lx = xc - (float)x0i;
            float hy = 1.f - ly, hx = 1.f - lx;
            float w00 = hy * hx, w01 = hy * lx, w10 = ly * hx, w11 = ly * lx;
            if (!valid) { w00 = 0.f; w01 = 0.f; w10 = 0.f; w11 = 0.f; }
            us8 r00 = *(const us8*)(fb + (size_t)(y0i * W_DIM + x0i) * 256 + c8);
            us8 r01 = *(const us8*)(fb + (size_t)(y0i * W_DIM + x1i) * 256 + c8);
            us8 r10 = *(const us8*)(fb + (size_t)(y1i * W_DIM + x0i) * 256 + c8);
            us8 r11 = *(const us8*)(fb + (size_t)(y1i * W_DIM + x1i) * 256 + c8);
            float accp = 0.f;
            #pragma unroll
            for (int j = 0; j < 8; j++) {
                float v = w00 * bfu(r00[j]) + w01 * bfu(r01[j])
                        + w10 * bfu(r10[j]) + w11 * bfu(r11[j]);
                sv[p][j] = v;
                accp = fmaf(uu[j], v, accp);
            }
            part[p] = accp;
        }
        #pragma unroll
        for (int mk = 1; mk <= 16; mk <<= 1) {
            #pragma unroll
            for (int p = 0; p < 4; p++) part[p] += __shfl_xor(part[p], mk, 64);
        }
        float sc0 = part[0] * SCALE, sc1 = part[1] * SCALE;
        float sc2 = part[2] * SCALE, sc3 = part[3] * SCALE;
        float mx = fmaxf(fmaxf(sc0, sc1), fmaxf(sc2, sc3));
        float e0 = __expf(sc0 - mx), e1 = __expf(sc1 - mx);
        float e2 = __expf(sc2 - mx), e3 = __expf(sc3 - mx);
        float inv = 1.f / (e0 + e1 + e2 + e3);
        us8 o8;
        #pragma unroll
        for (int j = 0; j < 8; j++) {
            float mv = (e0 * sv[0][j] + e1 * sv[1][j]
                      + e2 * sv[2][j] + e3 * sv[3][j]) * inv;
            o8[j] = f2bf_rne(mv);
        }
        *(us8*)(A + t * 264 + c8) = o8;
    }
    for (int i = tid; i < 480; i += 512) {         // zero pad rows 49..63
        int row = 49 + (i >> 5);
        int cs = (i & 31) * 8;
        us8 z = {0, 0, 0, 0, 0, 0, 0, 0};
        *(us8*)(A + row * 264 + cs) = z;
    }
    __syncthreads();

    int lane = tid & 63;
    int wave = tid >> 6;              // 0..7
    int col  = lane & 15;
    int quad = lane >> 4;
    int cbase = wave * 32;            // each wave: 32 out-channels x 64 rows

    f32x4 zero = {0.f, 0.f, 0.f, 0.f};
    f32x4 acc[4][2];                  // [rt][ct]
    #pragma unroll
    for (int i = 0; i < 4; i++)
        #pragma unroll
        for (int j = 0; j < 2; j++) acc[i][j] = zero;

    for (int ks = 0; ks < 8; ks++) {
        bf16x8 af[4];
        #pragma unroll
        for (int rt = 0; rt < 4; rt++)
            af[rt] = *(const bf16x8*)(A + (rt * 16 + col) * 264 + ks * 32 + quad * 8);
        #pragma unroll
        for (int ct = 0; ct < 2; ct++) {
            size_t bo = (size_t)(cbase + ct * 16 + col) * 256 + ks * 32 + quad * 8;
            bf16x8 bh8 = *(const bf16x8*)(Mh + bo);
            bf16x8 bl8 = *(const bf16x8*)(Ml + bo);
            #pragma unroll
            for (int rt = 0; rt < 4; rt++) {
                acc[rt][ct] = __builtin_amdgcn_mfma_f32_16x16x32_bf16(af[rt], bh8, acc[rt][ct], 0, 0, 0);
                acc[rt][ct] = __builtin_amdgcn_mfma_f32_16x16x32_bf16(af[rt], bl8, acc[rt][ct], 0, 0, 0);
            }
        }
    }

    __syncthreads();
    float* ostage = (float*)ldsraw;   // [256][53]
    #pragma unroll
    for (int rt = 0; rt < 4; rt++) {
        #pragma unroll
        for (int ct = 0; ct < 2; ct++) {
            int c = cbase + ct * 16 + col;
            float bias = c_out[c];
            #pragma unroll
            for (int rr = 0; rr < 4; rr++) {
                int tt = rt * 16 + quad * 4 + rr;
                if (tt < 49) ostage[c * 53 + tt] = acc[rt][ct][rr] + bias;
            }
        }
    }
    __syncthreads();
    float* ob = out + (size_t)n * 12544;
    #pragma unroll
    for (int k = 0; k < 25; k++) {
        int flat = k * 512 + tid;     // = c2*49 + t2
        if (flat < 12544) {
            int c2 = flat / 49;
            int t2 = flat - c2 * 49;
            ob[flat] = ostage[c2 * 53 + t2];
        }
    }
}

// ======= last-resort path if ws is too small for the NHWC feature copy =======
__global__ void sample_generic(const float* __restrict__ feat,
                               const float* __restrict__ rois,
                               const float* __restrict__ offs,
                               const float* __restrict__ u,
                               float* __restrict__ m_out) {
    __shared__ float red[4][4];
    int token = blockIdx.x;
    int n = token / 49;
    int t = token - n * 49;
    int h = t / 7;
    int w = t - h * 7;
    const float* r = rois + (size_t)n * 5;
    int bi   = (int)r[0];
    float x1 = r[1] * SPS - 0.5f;
    float y1 = r[2] * SPS - 0.5f;
    float rw = r[3] * SPS - 0.5f - x1;
    float rh = r[4] * SPS - 0.5f - y1;
    float bw = rw * (1.0f / 7.0f);
    float bh = rh * (1.0f / 7.0f);
    int c = threadIdx.x;
    const float* fb = feat + (size_t)bi * HW * C_DIM;
    float u_c = u[(size_t)t * 256 + c];
    float sv[4], part[4];
    #pragma unroll
    for (int p = 0; p < 4; p++) {
        float offw = offs[((p * 7 + h) * 7 + w) * 2 + 0];
        float offh = offs[((p * 7 + h) * 7 + w) * 2 + 1];
        float y = y1 + ((float)h + 0.5f) * bh + GAMMA * rh * offh;
        float x = x1 + ((float)w + 0.5f) * bw + GAMMA * rw * offw;
        bool valid = (y > -1.0f) && (y < (float)H_DIM) && (x > -1.0f) && (x < (float)W_DIM);
        float yc = fminf(fmaxf(y, 0.f), 127.f);
        float xc = fminf(fmaxf(x, 0.f), 127.f);
        int y0i = (int)floorf(yc);
        int x0i = (int)floorf(xc);
        int y1i = min(y0i + 1, 127);
        int x1i = min(x0i + 1, 127);
        float ly = yc - (float)y0i, lx = xc - (float)x0i;
        float hy = 1.f - ly, hx = 1.f - lx;
        float v00 = fb[(size_t)c * HW + y0i * W_DIM + x0i];
        float v01 = fb[(size_t)c * HW + y0i * W_DIM + x1i];
        float v10 = fb[(size_t)c * HW + y1i * W_DIM + x0i];
        float v11 = fb[(size_t)c * HW + y1i * W_DIM + x1i];
        float v = hy * hx * v00 + hy * lx * v01 + ly * hx * v10 + ly * lx * v11;
        v = valid ? v : 0.f;
        sv[p] = v;
        part[p] = u_c * v;
    }
    #pragma unroll
    for (int o = 32; o >= 1; o >>= 1) {
        #pragma unroll
        for (int p = 0; p < 4; p++) part[p] += __shfl_down(part[p], o, 64);
    }
    int wv = threadIdx.x >> 6, lane = threadIdx.x & 63;
    if (lane == 0) {
        red[wv][0] = part[0]; red[wv][1] = part[1];
        red[wv][2] = part[2]; red[wv][3] = part[3];
    }
    __syncthreads();
    float sc0 = (red[0][0] + red[1][0] + red[2][0] + red[3][0]) * SCALE;
    float sc1 = (red[0][1] + red[1][1] + red[2][1] + red[3][1]) * SCALE;
    float sc2 = (red[0][2] + red[1][2] + red[2][2] + red[3][2]) * SCALE;
    float sc3 = (red[0][3] + red[1][3] + red[2][3] + red[3][3]) * SCALE;
    float mx = fmaxf(fmaxf(sc0, sc1), fmaxf(sc2, sc3));
    float e0 = __expf(sc0 - mx), e1 = __expf(sc1 - mx);
    float e2 = __expf(sc2 - mx), e3 = __expf(sc3 - mx);
    float inv = 1.f / (e0 + e1 + e2 + e3);
    m_out[(size_t)token * 256 + c] =
        (e0 * sv[0] + e1 * sv[1] + e2 * sv[2] + e3 * sv[3]) * inv;
}

__global__ void __launch_bounds__(256) roi_gemm_m(const float* __restrict__ m,
                                                  const unsigned short* __restrict__ Mh,
                                                  const unsigned short* __restrict__ Ml,
                                                  const float* __restrict__ c_out,
                                                  float* __restrict__ out) {
    __shared__ __align__(16) char ldsraw[54272];
    unsigned short* A = (unsigned short*)ldsraw;
    int tid = threadIdx.x;
    int n = blockIdx.x;
    const float* mb = m + (size_t)n * 12544;
    for (int i = tid; i < 3136; i += 256) {
        float4 f = *(const float4*)(mb + (size_t)i * 4);
        int t = i >> 6;
        int d = (i & 63) * 4;
        unsigned short* dst = A + t * 264 + d;
        dst[0] = f2bf_rne(f.x); dst[1] = f2bf_rne(f.y);
        dst[2] = f2bf_rne(f.z); dst[3] = f2bf_rne(f.w);
    }
    for (int i = tid; i < 480; i += 256) {
        int row = 49 + (i >> 5);
        int cs = (i & 31) * 8;
        us8 z = {0,0,0,0,0,0,0,0};
        *(us8*)(A + row * 264 + cs) = z;
    }
    __syncthreads();
    int lane = tid & 63, wave = tid >> 6;
    int col = lane & 15, quad = lane >> 4;
    int cbase = wave * 64;
    f32x4 zero = {0.f,0.f,0.f,0.f};
    f32x4 acc[4][4];
    #pragma unroll
    for (int i = 0; i < 4; i++)
        #pragma unroll
        for (int j = 0; j < 4; j++) acc[i][j] = zero;
    for (int ks = 0; ks < 8; ks++) {
        bf16x8 af[4];
        #pragma unroll
        for (int rt = 0; rt < 4; rt++)
            af[rt] = *(const bf16x8*)(A + (rt * 16 + col) * 264 + ks * 32 + quad * 8);
        #pragma unroll
        for (int ct = 0; ct < 4; ct++) {
            size_t bo = (size_t)(cbase + ct * 16 + col) * 256 + ks * 32 + quad * 8;
            bf16x8 bh8 = *(const bf16x8*)(Mh + bo);
            bf16x8 bl8 = *(const bf16x8*)(Ml + bo);
            #pragma unroll
            for (int rt = 0; rt < 4; rt++) {
                acc[rt][ct] = __builtin_amdgcn_mfma_f32_16x16x32_bf16(af[rt], bh8, acc[rt][ct], 0, 0, 0);
                acc[rt][ct] = __builtin_amdgcn_mfma_f32_16x16x32_bf16(af[rt], bl8, acc[rt][ct], 0, 0, 0);
            }
        }
    }
    __syncthreads();
    float* ostage = (float*)ldsraw;
    #pragma unroll
    for (int rt = 0; rt < 4; rt++) {
        #pragma unroll
        for (int ct = 0; ct < 4; ct++) {
            int c = cbase + ct * 16 + col;
            float bias = c_out[c];
            #pragma unroll
            for (int rr = 0; rr < 4; rr++) {
                int tt = rt * 16 + quad * 4 + rr;
                if (tt < 49) ostage[c * 53 + tt] = acc[rt][ct][rr] + bias;
            }
        }
    }
    __syncthreads();
    float* ob = out + (size_t)n * 12544;
    for (int k = 0; k < 49; k++) {
        int flat = k * 256 + tid;
        int c2 = flat / 49;
        int t2 = flat - c2 * 49;
        ob[flat] = ostage[c2 * 53 + t2];
    }
}

extern "C" void kernel_launch(void* const* d_in, const int* in_sizes, int n_in,
                              void* d_out, int out_size, void* d_ws, size_t ws_size,
                              hipStream_t stream) {
    (void)in_sizes; (void)n_in; (void)out_size;
    const float* features   = (const float*)d_in[0];
    const float* rois       = (const float*)d_in[1];
    const float* offs       = (const float*)d_in[2];
    const float* queries    = (const float*)d_in[3];
    const float* w_proj     = (const float*)d_in[4];
    const float* b_proj     = (const float*)d_in[5];
    const float* in_proj_w  = (const float*)d_in[6];
    const float* in_proj_b  = (const float*)d_in[7];
    const float* out_proj_w = (const float*)d_in[8];
    const float* out_proj_b = (const float*)d_in[9];
    float* out = (float*)d_out;
    float* ws  = (float*)d_ws;

    float* A_k   = ws;                    // 65536
    float* A_v   = A_k  + 65536;          // 65536
    float* Qhat  = A_v  + 65536;          // 12544
    float* cv    = Qhat + 12544;          // 256
    float* u     = cv   + 256;            // 12544
    float* c_out = u    + 12544;          // 256   -> ends at 156672
    unsigned short* Mh = (unsigned short*)(ws + 156672);  // 65536 shorts
    unsigned short* Ml = (unsigned short*)(ws + 189440);  // 65536 shorts
    unsigned short* feat_b = (unsigned short*)(ws + 222208); // 16777216 shorts
    float* m_fb = ws + 222208;            // last-resort m buffer (overlaps feat_b)

    size_t needT = ((size_t)222208 + (size_t)8388608) * 4;
    size_t needF = ((size_t)222208 + (size_t)TOKENS * 256) * 4;
    bool useT = ws_size >= needT;

    if (useT) {
        k_init<<<4096 + 562, 256, 0, stream>>>(features, feat_b,
                                               w_proj, in_proj_w, in_proj_b,
                                               queries, b_proj,
                                               A_k, A_v, Qhat, cv);
        k_pre2<<<306, 256, 0, stream>>>(Qhat, A_k, A_v, out_proj_w, out_proj_b,
                                        cv, u, Mh, Ml, c_out);
        fused_sample_gemm<<<N_ROIS, 512, 0, stream>>>(feat_b, rois, offs, u,
                                                      Mh, Ml, c_out, out);
    } else {
        k_pre1<<<562, 256, 0, stream>>>(w_proj, in_proj_w, in_proj_b,
                                        queries, b_proj, A_k, A_v, Qhat, cv);
        k_pre2<<<306, 256, 0, stream>>>(Qhat, A_k, A_v, out_proj_w, out_proj_b,
                                        cv, u, Mh, Ml, c_out);
        float* m = (ws_size >= needF) ? m_fb : out;
        sample_generic<<<TOKENS, 256, 0, stream>>>(features, rois, offs, u, m);
        roi_gemm_m<<<N_ROIS, 256, 0, stream>>>(m, Mh, Ml, c_out, out);
    }
}